// Round 7
// baseline (153.663 us; speedup 1.0000x reference)
//
#include <hip/hip_runtime.h>
#include <hip/hip_bf16.h>
#include <math.h>

typedef __bf16 bf16x8 __attribute__((ext_vector_type(8)));
typedef __bf16 bf16x2 __attribute__((ext_vector_type(2)));
typedef short  s16x2  __attribute__((ext_vector_type(2)));
typedef short  s16x4  __attribute__((ext_vector_type(4)));
typedef float  floatx16 __attribute__((ext_vector_type(16)));

// Workspace layout (bytes):
//   Kq   bf16 [2][8192][16]   offset 0        (512 KB)  scaled by sqrt(log2 e)
//   Vswz bf16 [2][8192][32]   offset 524288   (1 MB)    B-frag swizzled order
//   Oacc f32  [2*8192][32]    offset 1572864  (2 MB)    atomic accumulator
//   Lacc f32  [2*8192]        offset 3669888  (64 KB)
#define KQ_ELEMS (2 * 8192 * 16)
#define OACC_OFF 1572864
#define SQRT_LOG2E 1.2011224087864498f
#define LSPLIT 4

// ---------------- Kernel A: zero accumulators + projections ----------------
__global__ __launch_bounds__(256) void proj_kernel(
    const float* __restrict__ in, const float* __restrict__ W1,
    const float* __restrict__ b1, const float* __restrict__ W2,
    const float* __restrict__ b2,
    __hip_bfloat16* __restrict__ Kq, __hip_bfloat16* __restrict__ Vswz,
    float* __restrict__ acc0)
{
    __shared__ float Xs[32][32];
    __shared__ float W1s[16 * 32];
    __shared__ float W2s[32 * 32];
    const int t = threadIdx.x;
    const int bid = blockIdx.x;       // 0..511
    const int b = bid >> 8;
    const int hw = bid & 255;

    // zero the accumulator region (Oacc 524288 floats + Lacc 16384 floats)
    {
        int gid = bid * 256 + t;                       // 0..131071
        *(float4*)(acc0 + (size_t)gid * 4) = make_float4(0.f, 0.f, 0.f, 0.f);
        if (gid < 4096)
            *(float4*)(acc0 + 524288 + (size_t)gid * 4) = make_float4(0.f, 0.f, 0.f, 0.f);
    }

    {
        int l = t >> 3, cs = (t & 7) * 4;
        float4 v = *(const float4*)(in + (((size_t)b * 32 + l) * 256 + hw) * 32 + cs);
        *(float4*)&Xs[l][cs] = v;
    }
    if (t < 128) *(float4*)&W1s[t * 4] = *(const float4*)(W1 + t * 4);
    *(float4*)&W2s[t * 4] = *(const float4*)(W2 + t * 4);
    __syncthreads();

    const int c = t & 31;
    const int g = t >> 5;             // 0..7

#pragma unroll
    for (int oo = 0; oo < 2; ++oo) {
        int o = g * 2 + oo;           // 0..15
        float acc = b1[o];
#pragma unroll
        for (int l = 0; l < 32; ++l) acc += W1s[o * 32 + l] * Xs[l][c];
        int k = c >> 1;
        int i = (c & 1) * 4096 + o * 256 + hw;
        Kq[((size_t)b * 8192 + i) * 16 + k] = __float2bfloat16(acc * SQRT_LOG2E);
    }
#pragma unroll
    for (int oo = 0; oo < 4; ++oo) {
        int o = g * 4 + oo;           // 0..31
        float acc = b2[o];
#pragma unroll
        for (int l = 0; l < 32; ++l) acc += W2s[o * 32 + l] * Xs[l][c];
        // position j = o*256 + hw, channel c; B-frag swizzle:
        // flat = jt*1024 + gg*256 + h*128 + c*4 + idx
        int j = o * 256 + hw;
        int jt = j >> 5, rem = j & 31;
        int gg = rem >> 3, h = (rem >> 2) & 1, idx = rem & 3;
        Vswz[(size_t)b * 262144 + jt * 1024 + gg * 256 + h * 128 + c * 4 + idx] =
            __float2bfloat16(acc);
    }
}

// ---------------- Kernel B: flash attention, LDS-free, atomic-accumulate ----------------
// block = 256 thr (4 waves), each wave owns 32 i-rows. grid = 2 * 64 * 16 = 2048.
__global__ __launch_bounds__(256, 8) void flash_kernel(
    const __hip_bfloat16* __restrict__ Kq, const __hip_bfloat16* __restrict__ Vswz,
    float* __restrict__ Oacc, float* __restrict__ Lacc)
{
    const int t = threadIdx.x;
    const int lane = t & 63;
    const int wv = t >> 6;            // 0..3
    const int m = lane & 31;
    const int h = lane >> 5;          // 0/1

    const int bid = blockIdx.x;
    const int s = bid & ((1 << LSPLIT) - 1);
    const int itile = (bid >> LSPLIT) & 63;
    const int b = bid >> (LSPLIT + 6);
    const int i0 = itile * 128 + wv * 32;
    const int niter = (8192 >> LSPLIT) >> 5;   // 16 tiles of 32 j
    const int jt0 = s * niter;

    const __hip_bfloat16* Kb = Kq + (size_t)b * 8192 * 16;
    const __hip_bfloat16* Vb = Vswz + (size_t)b * 262144 + h * 128 + m * 4;

    // Q B-frag (regs): B[k=8h+idx][n=m] = Kq[i0+m][8h+idx]
    const bf16x8 bq = *(const bf16x8*)(Kb + (size_t)(i0 + m) * 16 + h * 8);

    floatx16 oa = {}, ob = {};
    float2 l01 = {0.f, 0.f}, l23 = {0.f, 0.f};

    // prefetch it = 0
    bf16x8 ak = *(const bf16x8*)(Kb + (size_t)(jt0 * 32 + m) * 16 + h * 8);
    s16x4 vf0 = *(const s16x4*)(Vb + (size_t)jt0 * 1024 + 0);
    s16x4 vf1 = *(const s16x4*)(Vb + (size_t)jt0 * 1024 + 256);
    s16x4 vf2 = *(const s16x4*)(Vb + (size_t)jt0 * 1024 + 512);
    s16x4 vf3 = *(const s16x4*)(Vb + (size_t)jt0 * 1024 + 768);

    for (int it = 0; it < niter; ++it) {
        const int jtn = jt0 + (it + 1 < niter ? it + 1 : it);
        bf16x8 ak_n = *(const bf16x8*)(Kb + (size_t)(jtn * 32 + m) * 16 + h * 8);
        s16x4 vn0 = *(const s16x4*)(Vb + (size_t)jtn * 1024 + 0);
        s16x4 vn1 = *(const s16x4*)(Vb + (size_t)jtn * 1024 + 256);
        s16x4 vn2 = *(const s16x4*)(Vb + (size_t)jtn * 1024 + 512);
        s16x4 vn3 = *(const s16x4*)(Vb + (size_t)jtn * 1024 + 768);

        // S^T(32j x 32i) = K(A) x Q(B), K=16 exact
        floatx16 sc = __builtin_amdgcn_mfma_f32_32x32x16_bf16(ak, bq, (floatx16){}, 0, 0, 0);

        // P = 2^S ; reg 4g+idx holds j_loc = 8g+4h+idx == 32x32x8 A-layout.
#pragma unroll
        for (int g = 0; g < 4; ++g) {
            float e0 = __builtin_amdgcn_exp2f(sc[4 * g + 0]);
            float e1 = __builtin_amdgcn_exp2f(sc[4 * g + 1]);
            float e2 = __builtin_amdgcn_exp2f(sc[4 * g + 2]);
            float e3 = __builtin_amdgcn_exp2f(sc[4 * g + 3]);
            l01.x += e0; l01.y += e1; l23.x += e2; l23.y += e3;
#if defined(__has_builtin) && __has_builtin(__builtin_amdgcn_cvt_pk_bf16_f32)
            bf16x2 plo = __builtin_amdgcn_cvt_pk_bf16_f32(e0, e1);
            bf16x2 phi = __builtin_amdgcn_cvt_pk_bf16_f32(e2, e3);
#else
            bf16x2 plo = {(__bf16)e0, (__bf16)e1};
            bf16x2 phi = {(__bf16)e2, (__bf16)e3};
#endif
            s16x2 lo = __builtin_bit_cast(s16x2, plo);
            s16x2 hi = __builtin_bit_cast(s16x2, phi);
            s16x4 pb = {lo[0], lo[1], hi[0], hi[1]};
            s16x4 vf = (g == 0) ? vf0 : (g == 1) ? vf1 : (g == 2) ? vf2 : vf3;
            if (g < 2)
                oa = __builtin_amdgcn_mfma_f32_32x32x8bf16_1k(pb, vf, oa, 0, 0, 0);
            else
                ob = __builtin_amdgcn_mfma_f32_32x32x8bf16_1k(pb, vf, ob, 0, 0, 0);
        }
        ak = ak_n; vf0 = vn0; vf1 = vn1; vf2 = vn2; vf3 = vn3;
    }

    oa = oa + ob;
    float l = (l01.x + l01.y) + (l23.x + l23.y);
    l += __shfl_xor(l, 32);

    // atomic-accumulate partials (plain sums: no max-rescaling in this scheme)
    // reg r -> row i_loc=(r&3)+8*(r>>2)+4h, col c=m
#pragma unroll
    for (int r = 0; r < 16; ++r) {
        int iloc = (r & 3) + 8 * (r >> 2) + 4 * h;
        size_t row = (size_t)b * 8192 + i0 + iloc;
        unsafeAtomicAdd(&Oacc[row * 32 + m], oa[r]);
    }
    if (h == 0)
        unsafeAtomicAdd(&Lacc[(size_t)b * 8192 + i0 + m], l);
}

// ---------------- Kernel C: normalize + epilogue ----------------
__global__ __launch_bounds__(256) void finalize_kernel(
    const float* __restrict__ Oacc, const float* __restrict__ Lacc,
    const float* __restrict__ in, const float* __restrict__ gamma,
    float* __restrict__ out)
{
    const int t = threadIdx.x;
    const int c = t & 31;
    const size_t row = (size_t)blockIdx.x * 8 + (t >> 5);
    size_t idx = row * 32 + c;
    out[idx] = (Oacc[idx] / Lacc[row]) * gamma[0] + in[idx];
}

extern "C" void kernel_launch(void* const* d_in, const int* in_sizes, int n_in,
                              void* d_out, int out_size, void* d_ws, size_t ws_size,
                              hipStream_t stream) {
    const float* in = (const float*)d_in[0];
    const float* W1 = (const float*)d_in[1];
    const float* b1 = (const float*)d_in[2];
    const float* W2 = (const float*)d_in[3];
    const float* b2 = (const float*)d_in[4];
    const float* gamma = (const float*)d_in[5];
    float* out = (float*)d_out;

    __hip_bfloat16* Kq = (__hip_bfloat16*)d_ws;
    __hip_bfloat16* Vswz = Kq + KQ_ELEMS;
    float* Oacc = (float*)((char*)d_ws + OACC_OFF);
    float* Lacc = Oacc + 16384 * 32;

    proj_kernel<<<512, 256, 0, stream>>>(in, W1, b1, W2, b2, Kq, Vswz, Oacc);
    flash_kernel<<<2 * 64 * (1 << LSPLIT), 256, 0, stream>>>(Kq, Vswz, Oacc, Lacc);
    finalize_kernel<<<2048, 256, 0, stream>>>(Oacc, Lacc, in, gamma, out);
}

// Round 8
// 112.352 us; speedup vs baseline: 1.3677x; 1.3677x over previous
//
#include <hip/hip_runtime.h>
#include <hip/hip_bf16.h>
#include <math.h>

typedef __bf16 bf16x8 __attribute__((ext_vector_type(8)));
typedef __bf16 bf16x2 __attribute__((ext_vector_type(2)));
typedef short  s16x2  __attribute__((ext_vector_type(2)));
typedef short  s16x4  __attribute__((ext_vector_type(4)));
typedef float  floatx16 __attribute__((ext_vector_type(16)));

// Workspace layout (bytes):
//   Kq   bf16 [2][8192][16]   offset 0        (512 KB)  scaled by sqrt(log2 e)
//   Vswz bf16 [2][8192][32]   offset 524288   (1 MB)    B-frag swizzled order
//   Oacc f32  [2*8192][32]    offset 1572864  (2 MB)    atomic accumulator
//   Lacc f32  [2*8192]        offset 3669888  (64 KB)
#define KQ_ELEMS (2 * 8192 * 16)
#define OACC_OFF 1572864
#define SQRT_LOG2E 1.2011224087864498f
#define LSPLIT 4

// ---------------- Kernel A: zero accumulators + projections ----------------
__global__ __launch_bounds__(256) void proj_kernel(
    const float* __restrict__ in, const float* __restrict__ W1,
    const float* __restrict__ b1, const float* __restrict__ W2,
    const float* __restrict__ b2,
    __hip_bfloat16* __restrict__ Kq, __hip_bfloat16* __restrict__ Vswz,
    float* __restrict__ acc0)
{
    __shared__ float Xs[32][32];
    __shared__ float W1s[16 * 32];
    __shared__ float W2s[32 * 32];
    const int t = threadIdx.x;
    const int bid = blockIdx.x;       // 0..511
    const int b = bid >> 8;
    const int hw = bid & 255;

    // zero the accumulator region (Oacc 524288 floats + Lacc 16384 floats)
    {
        int gid = bid * 256 + t;                       // 0..131071
        *(float4*)(acc0 + (size_t)gid * 4) = make_float4(0.f, 0.f, 0.f, 0.f);
        if (gid < 4096)
            *(float4*)(acc0 + 524288 + (size_t)gid * 4) = make_float4(0.f, 0.f, 0.f, 0.f);
    }

    {
        int l = t >> 3, cs = (t & 7) * 4;
        float4 v = *(const float4*)(in + (((size_t)b * 32 + l) * 256 + hw) * 32 + cs);
        *(float4*)&Xs[l][cs] = v;
    }
    if (t < 128) *(float4*)&W1s[t * 4] = *(const float4*)(W1 + t * 4);
    *(float4*)&W2s[t * 4] = *(const float4*)(W2 + t * 4);
    __syncthreads();

    const int c = t & 31;
    const int g = t >> 5;             // 0..7

#pragma unroll
    for (int oo = 0; oo < 2; ++oo) {
        int o = g * 2 + oo;           // 0..15
        float acc = b1[o];
#pragma unroll
        for (int l = 0; l < 32; ++l) acc += W1s[o * 32 + l] * Xs[l][c];
        int k = c >> 1;
        int i = (c & 1) * 4096 + o * 256 + hw;
        Kq[((size_t)b * 8192 + i) * 16 + k] = __float2bfloat16(acc * SQRT_LOG2E);
    }
#pragma unroll
    for (int oo = 0; oo < 4; ++oo) {
        int o = g * 4 + oo;           // 0..31
        float acc = b2[o];
#pragma unroll
        for (int l = 0; l < 32; ++l) acc += W2s[o * 32 + l] * Xs[l][c];
        // position j = o*256 + hw, channel c; B-frag swizzle:
        // flat = jt*1024 + gg*256 + h*128 + c*4 + idx
        int j = o * 256 + hw;
        int jt = j >> 5, rem = j & 31;
        int gg = rem >> 3, h = (rem >> 2) & 1, idx = rem & 3;
        Vswz[(size_t)b * 262144 + jt * 1024 + gg * 256 + h * 128 + c * 4 + idx] =
            __float2bfloat16(acc);
    }
}

// ---------------- Kernel B: flash attention, LDS-free, atomic-accumulate ----------------
// block = 256 thr (4 waves), each wave owns 32 i-rows. grid = 2 * 64 * 16 = 2048.
// NOTE: no min-waves arg in __launch_bounds__ — forcing 8 waves/EU capped VGPR
// at 32 and spilled the accumulators to scratch (R7: +65 MB HBM traffic, 2x dur).
__global__ __launch_bounds__(256) void flash_kernel(
    const __hip_bfloat16* __restrict__ Kq, const __hip_bfloat16* __restrict__ Vswz,
    float* __restrict__ Oacc, float* __restrict__ Lacc)
{
    const int t = threadIdx.x;
    const int lane = t & 63;
    const int wv = t >> 6;            // 0..3
    const int m = lane & 31;
    const int h = lane >> 5;          // 0/1

    const int bid = blockIdx.x;
    const int s = bid & ((1 << LSPLIT) - 1);
    const int itile = (bid >> LSPLIT) & 63;
    const int b = bid >> (LSPLIT + 6);
    const int i0 = itile * 128 + wv * 32;
    const int niter = (8192 >> LSPLIT) >> 5;   // 16 tiles of 32 j
    const int jt0 = s * niter;

    const __hip_bfloat16* Kb = Kq + (size_t)b * 8192 * 16;
    const __hip_bfloat16* Vb = Vswz + (size_t)b * 262144 + h * 128 + m * 4;

    // Q B-frag (regs): B[k=8h+idx][n=m] = Kq[i0+m][8h+idx]
    const bf16x8 bq = *(const bf16x8*)(Kb + (size_t)(i0 + m) * 16 + h * 8);

    floatx16 oa = {}, ob = {};
    float2 l01 = {0.f, 0.f}, l23 = {0.f, 0.f};

    // prefetch it = 0
    bf16x8 ak = *(const bf16x8*)(Kb + (size_t)(jt0 * 32 + m) * 16 + h * 8);
    s16x4 vf0 = *(const s16x4*)(Vb + (size_t)jt0 * 1024 + 0);
    s16x4 vf1 = *(const s16x4*)(Vb + (size_t)jt0 * 1024 + 256);
    s16x4 vf2 = *(const s16x4*)(Vb + (size_t)jt0 * 1024 + 512);
    s16x4 vf3 = *(const s16x4*)(Vb + (size_t)jt0 * 1024 + 768);

    for (int it = 0; it < niter; ++it) {
        const int jtn = jt0 + (it + 1 < niter ? it + 1 : it);
        bf16x8 ak_n = *(const bf16x8*)(Kb + (size_t)(jtn * 32 + m) * 16 + h * 8);
        s16x4 vn0 = *(const s16x4*)(Vb + (size_t)jtn * 1024 + 0);
        s16x4 vn1 = *(const s16x4*)(Vb + (size_t)jtn * 1024 + 256);
        s16x4 vn2 = *(const s16x4*)(Vb + (size_t)jtn * 1024 + 512);
        s16x4 vn3 = *(const s16x4*)(Vb + (size_t)jtn * 1024 + 768);

        // S^T(32j x 32i) = K(A) x Q(B), K=16 exact
        floatx16 sc = __builtin_amdgcn_mfma_f32_32x32x16_bf16(ak, bq, (floatx16){}, 0, 0, 0);

        // P = 2^S ; reg 4g+idx holds j_loc = 8g+4h+idx == 32x32x8 A-layout.
#pragma unroll
        for (int g = 0; g < 4; ++g) {
            float e0 = __builtin_amdgcn_exp2f(sc[4 * g + 0]);
            float e1 = __builtin_amdgcn_exp2f(sc[4 * g + 1]);
            float e2 = __builtin_amdgcn_exp2f(sc[4 * g + 2]);
            float e3 = __builtin_amdgcn_exp2f(sc[4 * g + 3]);
            l01.x += e0; l01.y += e1; l23.x += e2; l23.y += e3;
#if defined(__has_builtin) && __has_builtin(__builtin_amdgcn_cvt_pk_bf16_f32)
            bf16x2 plo = __builtin_amdgcn_cvt_pk_bf16_f32(e0, e1);
            bf16x2 phi = __builtin_amdgcn_cvt_pk_bf16_f32(e2, e3);
#else
            bf16x2 plo = {(__bf16)e0, (__bf16)e1};
            bf16x2 phi = {(__bf16)e2, (__bf16)e3};
#endif
            s16x2 lo = __builtin_bit_cast(s16x2, plo);
            s16x2 hi = __builtin_bit_cast(s16x2, phi);
            s16x4 pb = {lo[0], lo[1], hi[0], hi[1]};
            s16x4 vf = (g == 0) ? vf0 : (g == 1) ? vf1 : (g == 2) ? vf2 : vf3;
            if (g < 2)
                oa = __builtin_amdgcn_mfma_f32_32x32x8bf16_1k(pb, vf, oa, 0, 0, 0);
            else
                ob = __builtin_amdgcn_mfma_f32_32x32x8bf16_1k(pb, vf, ob, 0, 0, 0);
        }
        ak = ak_n; vf0 = vn0; vf1 = vn1; vf2 = vn2; vf3 = vn3;
    }

    oa = oa + ob;
    float l = (l01.x + l01.y) + (l23.x + l23.y);
    l += __shfl_xor(l, 32);

    // atomic-accumulate partials (plain sums: no max-rescaling in this scheme)
    // reg r -> row i_loc=(r&3)+8*(r>>2)+4h, col c=m
#pragma unroll
    for (int r = 0; r < 16; ++r) {
        int iloc = (r & 3) + 8 * (r >> 2) + 4 * h;
        size_t row = (size_t)b * 8192 + i0 + iloc;
        unsafeAtomicAdd(&Oacc[row * 32 + m], oa[r]);
    }
    if (h == 0)
        unsafeAtomicAdd(&Lacc[(size_t)b * 8192 + i0 + m], l);
}

// ---------------- Kernel C: normalize + epilogue ----------------
__global__ __launch_bounds__(256) void finalize_kernel(
    const float* __restrict__ Oacc, const float* __restrict__ Lacc,
    const float* __restrict__ in, const float* __restrict__ gamma,
    float* __restrict__ out)
{
    const int t = threadIdx.x;
    const int c = t & 31;
    const size_t row = (size_t)blockIdx.x * 8 + (t >> 5);
    size_t idx = row * 32 + c;
    out[idx] = (Oacc[idx] / Lacc[row]) * gamma[0] + in[idx];
}

extern "C" void kernel_launch(void* const* d_in, const int* in_sizes, int n_in,
                              void* d_out, int out_size, void* d_ws, size_t ws_size,
                              hipStream_t stream) {
    const float* in = (const float*)d_in[0];
    const float* W1 = (const float*)d_in[1];
    const float* b1 = (const float*)d_in[2];
    const float* W2 = (const float*)d_in[3];
    const float* b2 = (const float*)d_in[4];
    const float* gamma = (const float*)d_in[5];
    float* out = (float*)d_out;

    __hip_bfloat16* Kq = (__hip_bfloat16*)d_ws;
    __hip_bfloat16* Vswz = Kq + KQ_ELEMS;
    float* Oacc = (float*)((char*)d_ws + OACC_OFF);
    float* Lacc = Oacc + 16384 * 32;

    proj_kernel<<<512, 256, 0, stream>>>(in, W1, b1, W2, b2, Kq, Vswz, Oacc);
    flash_kernel<<<2 * 64 * (1 << LSPLIT), 256, 0, stream>>>(Kq, Vswz, Oacc, Lacc);
    finalize_kernel<<<2048, 256, 0, stream>>>(Oacc, Lacc, in, gamma, out);
}

// Round 9
// 112.271 us; speedup vs baseline: 1.3687x; 1.0007x over previous
//
#include <hip/hip_runtime.h>
#include <hip/hip_bf16.h>
#include <math.h>

typedef __bf16 bf16x8 __attribute__((ext_vector_type(8)));
typedef __bf16 bf16x2 __attribute__((ext_vector_type(2)));
typedef short  s16x2  __attribute__((ext_vector_type(2)));
typedef short  s16x4  __attribute__((ext_vector_type(4)));
typedef float  floatx16 __attribute__((ext_vector_type(16)));

// Workspace layout (bytes):
//   Kq   bf16 [2][8192][16]   offset 0        (512 KB)  scaled by sqrt(log2 e)
//   Vswz bf16 [2][8192][32]   offset 524288   (1 MB)    B-frag swizzled order
//   Oacc f32  [2*8192][32]    offset 1572864  (2 MB)    atomic accumulator
//   Lacc f32  [2*8192]        offset 3669888  (64 KB)
#define KQ_ELEMS (2 * 8192 * 16)
#define OACC_OFF 1572864
#define SQRT_LOG2E 1.2011224087864498f
#define LSPLIT 4

// ---------------- Kernel A: zero accumulators + projections ----------------
__global__ __launch_bounds__(256) void proj_kernel(
    const float* __restrict__ in, const float* __restrict__ W1,
    const float* __restrict__ b1, const float* __restrict__ W2,
    const float* __restrict__ b2,
    __hip_bfloat16* __restrict__ Kq, __hip_bfloat16* __restrict__ Vswz,
    float* __restrict__ acc0)
{
    __shared__ float Xs[32][32];
    __shared__ float W1s[16 * 32];
    __shared__ float W2s[32 * 32];
    const int t = threadIdx.x;
    const int bid = blockIdx.x;       // 0..511
    const int b = bid >> 8;
    const int hw = bid & 255;

    // zero the accumulator region (Oacc 524288 floats + Lacc 16384 floats)
    {
        int gid = bid * 256 + t;                       // 0..131071
        *(float4*)(acc0 + (size_t)gid * 4) = make_float4(0.f, 0.f, 0.f, 0.f);
        if (gid < 4096)
            *(float4*)(acc0 + 524288 + (size_t)gid * 4) = make_float4(0.f, 0.f, 0.f, 0.f);
    }

    {
        int l = t >> 3, cs = (t & 7) * 4;
        float4 v = *(const float4*)(in + (((size_t)b * 32 + l) * 256 + hw) * 32 + cs);
        *(float4*)&Xs[l][cs] = v;
    }
    if (t < 128) *(float4*)&W1s[t * 4] = *(const float4*)(W1 + t * 4);
    *(float4*)&W2s[t * 4] = *(const float4*)(W2 + t * 4);
    __syncthreads();

    const int c = t & 31;
    const int g = t >> 5;             // 0..7

#pragma unroll
    for (int oo = 0; oo < 2; ++oo) {
        int o = g * 2 + oo;           // 0..15
        float acc = b1[o];
#pragma unroll
        for (int l = 0; l < 32; ++l) acc += W1s[o * 32 + l] * Xs[l][c];
        int k = c >> 1;
        int i = (c & 1) * 4096 + o * 256 + hw;
        Kq[((size_t)b * 8192 + i) * 16 + k] = __float2bfloat16(acc * SQRT_LOG2E);
    }
#pragma unroll
    for (int oo = 0; oo < 4; ++oo) {
        int o = g * 4 + oo;           // 0..31
        float acc = b2[o];
#pragma unroll
        for (int l = 0; l < 32; ++l) acc += W2s[o * 32 + l] * Xs[l][c];
        // position j = o*256 + hw, channel c; B-frag swizzle:
        // flat = jt*1024 + gg*256 + h*128 + c*4 + idx
        int j = o * 256 + hw;
        int jt = j >> 5, rem = j & 31;
        int gg = rem >> 3, h = (rem >> 2) & 1, idx = rem & 3;
        Vswz[(size_t)b * 262144 + jt * 1024 + gg * 256 + h * 128 + c * 4 + idx] =
            __float2bfloat16(acc);
    }
}

// ---------------- Kernel B: flash attention, dual-stream pair-unrolled ----------------
// block = 256 thr (4 waves), each wave owns 32 i-rows. grid = 2 * 64 * 16 = 2048.
// NOTE: no min-waves arg in __launch_bounds__ — forcing 8 waves/EU capped VGPR
// at 32 and spilled the accumulators to scratch (R7: +65 MB HBM traffic, 2x dur).
struct Frags { bf16x8 ak; s16x4 v0, v1, v2, v3; };

__global__ __launch_bounds__(256) void flash_kernel(
    const __hip_bfloat16* __restrict__ Kq, const __hip_bfloat16* __restrict__ Vswz,
    float* __restrict__ Oacc, float* __restrict__ Lacc)
{
    const int t = threadIdx.x;
    const int lane = t & 63;
    const int wv = t >> 6;            // 0..3
    const int m = lane & 31;
    const int h = lane >> 5;          // 0/1

    const int bid = blockIdx.x;
    const int s = bid & ((1 << LSPLIT) - 1);
    const int itile = (bid >> LSPLIT) & 63;
    const int b = bid >> (LSPLIT + 6);
    const int i0 = itile * 128 + wv * 32;
    const int niter = (8192 >> LSPLIT) >> 5;   // 16 tiles of 32 j
    const int jt0 = s * niter;

    const __hip_bfloat16* Kb = Kq + (size_t)b * 8192 * 16;
    const __hip_bfloat16* Vb = Vswz + (size_t)b * 262144 + h * 128 + m * 4;

    // Q B-frag (regs): B[k=8h+idx][n=m] = Kq[i0+m][8h+idx]
    const bf16x8 bq = *(const bf16x8*)(Kb + (size_t)(i0 + m) * 16 + h * 8);

    floatx16 oa = {}, ob = {};
    float2 la = {0.f, 0.f}, lb = {0.f, 0.f};

    auto load = [&](int jt) {
        Frags f;
        f.ak = *(const bf16x8*)(Kb + (size_t)(jt * 32 + m) * 16 + h * 8);
        const __hip_bfloat16* vp = Vb + (size_t)jt * 1024;
        f.v0 = *(const s16x4*)(vp + 0);
        f.v1 = *(const s16x4*)(vp + 256);
        f.v2 = *(const s16x4*)(vp + 512);
        f.v3 = *(const s16x4*)(vp + 768);
        return f;
    };

    // prefetch pair 0
    Frags f0 = load(jt0);
    Frags f1 = load(jt0 + 1);

    for (int it = 0; it < niter; it += 2) {
        // prefetch next pair (clamped on last pair: re-loads current, harmless)
        const int n0i = it + 2 < niter ? it + 2 : it;
        const int n1i = it + 3 < niter ? it + 3 : it + 1;
        Frags n0 = load(jt0 + n0i);
        Frags n1 = load(jt0 + n1i);

        // two independent S^T tiles issued back-to-back
        floatx16 sc0 = __builtin_amdgcn_mfma_f32_32x32x16_bf16(f0.ak, bq, (floatx16){}, 0, 0, 0);
        floatx16 sc1 = __builtin_amdgcn_mfma_f32_32x32x16_bf16(f1.ak, bq, (floatx16){}, 0, 0, 0);

        // P = 2^S ; reg 4g+idx holds j_loc = 8g+4h+idx == 32x32x8 A-layout.
        // stream 0 -> oa / la ; stream 1 -> ob / lb (independent chains)
#pragma unroll
        for (int g = 0; g < 4; ++g) {
            {
                float e0 = __builtin_amdgcn_exp2f(sc0[4 * g + 0]);
                float e1 = __builtin_amdgcn_exp2f(sc0[4 * g + 1]);
                float e2 = __builtin_amdgcn_exp2f(sc0[4 * g + 2]);
                float e3 = __builtin_amdgcn_exp2f(sc0[4 * g + 3]);
                la.x += e0; la.y += e1; la.x += e2; la.y += e3;
#if defined(__has_builtin) && __has_builtin(__builtin_amdgcn_cvt_pk_bf16_f32)
                bf16x2 plo = __builtin_amdgcn_cvt_pk_bf16_f32(e0, e1);
                bf16x2 phi = __builtin_amdgcn_cvt_pk_bf16_f32(e2, e3);
#else
                bf16x2 plo = {(__bf16)e0, (__bf16)e1};
                bf16x2 phi = {(__bf16)e2, (__bf16)e3};
#endif
                s16x2 lo = __builtin_bit_cast(s16x2, plo);
                s16x2 hi = __builtin_bit_cast(s16x2, phi);
                s16x4 pb = {lo[0], lo[1], hi[0], hi[1]};
                s16x4 vf = (g == 0) ? f0.v0 : (g == 1) ? f0.v1 : (g == 2) ? f0.v2 : f0.v3;
                oa = __builtin_amdgcn_mfma_f32_32x32x8bf16_1k(pb, vf, oa, 0, 0, 0);
            }
            {
                float e0 = __builtin_amdgcn_exp2f(sc1[4 * g + 0]);
                float e1 = __builtin_amdgcn_exp2f(sc1[4 * g + 1]);
                float e2 = __builtin_amdgcn_exp2f(sc1[4 * g + 2]);
                float e3 = __builtin_amdgcn_exp2f(sc1[4 * g + 3]);
                lb.x += e0; lb.y += e1; lb.x += e2; lb.y += e3;
#if defined(__has_builtin) && __has_builtin(__builtin_amdgcn_cvt_pk_bf16_f32)
                bf16x2 plo = __builtin_amdgcn_cvt_pk_bf16_f32(e0, e1);
                bf16x2 phi = __builtin_amdgcn_cvt_pk_bf16_f32(e2, e3);
#else
                bf16x2 plo = {(__bf16)e0, (__bf16)e1};
                bf16x2 phi = {(__bf16)e2, (__bf16)e3};
#endif
                s16x2 lo = __builtin_bit_cast(s16x2, plo);
                s16x2 hi = __builtin_bit_cast(s16x2, phi);
                s16x4 pb = {lo[0], lo[1], hi[0], hi[1]};
                s16x4 vf = (g == 0) ? f1.v0 : (g == 1) ? f1.v1 : (g == 2) ? f1.v2 : f1.v3;
                ob = __builtin_amdgcn_mfma_f32_32x32x8bf16_1k(pb, vf, ob, 0, 0, 0);
            }
        }
        f0 = n0; f1 = n1;
    }

    oa = oa + ob;
    float l = (la.x + la.y) + (lb.x + lb.y);
    l += __shfl_xor(l, 32);

    // atomic-accumulate partials (plain sums: no max-rescaling in this scheme)
    // reg r -> row i_loc=(r&3)+8*(r>>2)+4h, col c=m
#pragma unroll
    for (int r = 0; r < 16; ++r) {
        int iloc = (r & 3) + 8 * (r >> 2) + 4 * h;
        size_t row = (size_t)b * 8192 + i0 + iloc;
        unsafeAtomicAdd(&Oacc[row * 32 + m], oa[r]);
    }
    if (h == 0)
        unsafeAtomicAdd(&Lacc[(size_t)b * 8192 + i0 + m], l);
}

// ---------------- Kernel C: normalize + epilogue ----------------
__global__ __launch_bounds__(256) void finalize_kernel(
    const float* __restrict__ Oacc, const float* __restrict__ Lacc,
    const float* __restrict__ in, const float* __restrict__ gamma,
    float* __restrict__ out)
{
    const int t = threadIdx.x;
    const int c = t & 31;
    const size_t row = (size_t)blockIdx.x * 8 + (t >> 5);
    size_t idx = row * 32 + c;
    out[idx] = (Oacc[idx] / Lacc[row]) * gamma[0] + in[idx];
}

extern "C" void kernel_launch(void* const* d_in, const int* in_sizes, int n_in,
                              void* d_out, int out_size, void* d_ws, size_t ws_size,
                              hipStream_t stream) {
    const float* in = (const float*)d_in[0];
    const float* W1 = (const float*)d_in[1];
    const float* b1 = (const float*)d_in[2];
    const float* W2 = (const float*)d_in[3];
    const float* b2 = (const float*)d_in[4];
    const float* gamma = (const float*)d_in[5];
    float* out = (float*)d_out;

    __hip_bfloat16* Kq = (__hip_bfloat16*)d_ws;
    __hip_bfloat16* Vswz = Kq + KQ_ELEMS;
    float* Oacc = (float*)((char*)d_ws + OACC_OFF);
    float* Lacc = Oacc + 16384 * 32;

    proj_kernel<<<512, 256, 0, stream>>>(in, W1, b1, W2, b2, Kq, Vswz, Oacc);
    flash_kernel<<<2 * 64 * (1 << LSPLIT), 256, 0, stream>>>(Kq, Vswz, Oacc, Lacc);
    finalize_kernel<<<2048, 256, 0, stream>>>(Oacc, Lacc, in, gamma, out);
}